// Round 1
// baseline (497.111 us; speedup 1.0000x reference)
//
#include <hip/hip_runtime.h>
#include <math.h>

#define NE 8
#define HD 2048
#define ID 1408
#define NT 512
#define NENT 1024
#define FP8MAX 448.0f

typedef __attribute__((ext_vector_type(4))) float floatx4;

__device__ __forceinline__ floatx4 fzero4() {
    floatx4 z; z.x = 0.f; z.y = 0.f; z.z = 0.f; z.w = 0.f; return z;
}

// ---- ws layout (bytes), all 256-aligned ----
#define OFF_OFFS  0                         // int[16]
#define OFF_TOK   1024                      // int[1024]
#define OFF_WGT   8192                      // float[1024]
#define OFF_XS    16384                     // float[512*16]
#define OFF_XQ    65536                     // u8[512*2048]  (1 MiB)
#define OFF_HS    (2*1024*1024)             // float[1024*11]
#define OFF_HQ    (2*1024*1024 + 65536)     // u8[1024*1408]
#define OFF_H32   (4*1024*1024)             // float[1024*1408]

// ---------------- routing: build per-expert compact entry lists ----------------
__global__ void route_kernel(const int* __restrict__ tki,
                             const float* __restrict__ tkw,
                             int* __restrict__ offs,
                             int* __restrict__ tok,
                             float* __restrict__ wgt) {
    __shared__ int cnt[NE];
    __shared__ int cur[NE];
    __shared__ int base[NE + 1];
    int tid = threadIdx.x;               // 1024 threads, one per (token, slot)
    if (tid < NE) { cnt[tid] = 0; cur[tid] = 0; }
    __syncthreads();
    int e = tki[tid];
    atomicAdd(&cnt[e], 1);
    __syncthreads();
    if (tid == 0) {
        int s = 0;
        for (int i = 0; i < NE; i++) { base[i] = s; s += cnt[i]; }
        base[NE] = s;
    }
    __syncthreads();
    int pos = atomicAdd(&cur[e], 1);
    int j = base[e] + pos;
    tok[j] = tid >> 1;                   // token id
    wgt[j] = tkw[tid];
    if (tid <= NE) offs[tid] = base[tid];
}

// ---------------- activation quantization: wave per (token, 128-block) --------
__global__ void quant_x_kernel(const float* __restrict__ x,
                               unsigned char* __restrict__ xq,
                               float* __restrict__ xs) {
    int wid = (blockIdx.x * 256 + threadIdx.x) >> 6;   // 0..8191
    int lane = threadIdx.x & 63;
    int t = wid >> 4;
    int b = wid & 15;
    const float2 v = *(const float2*)(x + (long)t * HD + b * 128 + lane * 2);
    float am = fmaxf(fabsf(v.x), fabsf(v.y));
    #pragma unroll
    for (int m = 32; m; m >>= 1) am = fmaxf(am, __shfl_xor(am, m));
    float scale = fmaxf(am, 1e-12f) / FP8MAX;
    int p = __builtin_amdgcn_cvt_pk_fp8_f32(v.x / scale, v.y / scale, 0, false);
    *(unsigned short*)(xq + (long)t * HD + b * 128 + lane * 2) =
        (unsigned short)(p & 0xffff);
    if (lane == 0) xs[t * 16 + b] = scale;
}

// ---------------- h quantization: wave per (entry, 128-block of 11) ----------
__global__ void quant_h_kernel(const float* __restrict__ h32,
                               unsigned char* __restrict__ hq,
                               float* __restrict__ hs) {
    int wid = (blockIdx.x * 256 + threadIdx.x) >> 6;   // 0..11263
    int lane = threadIdx.x & 63;
    int j = wid / 11;
    int b = wid - j * 11;
    const float2 v = *(const float2*)(h32 + (long)j * ID + b * 128 + lane * 2);
    float am = fmaxf(fabsf(v.x), fabsf(v.y));
    #pragma unroll
    for (int m = 32; m; m >>= 1) am = fmaxf(am, __shfl_xor(am, m));
    float scale = fmaxf(am, 1e-12f) / FP8MAX;
    int p = __builtin_amdgcn_cvt_pk_fp8_f32(v.x / scale, v.y / scale, 0, false);
    *(unsigned short*)(hq + (long)j * ID + b * 128 + lane * 2) =
        (unsigned short)(p & 0xffff);
    if (lane == 0) hs[j * 11 + b] = scale;
}

// ---------------- gemm1: routed x @ Wgu^T, silu*up fused, h32 out ------------
#define LDA 144
#define LDB 144

__global__ __launch_bounds__(256) void gemm1_kernel(
    const unsigned char* __restrict__ xq,
    const float* __restrict__ xs,
    const float* __restrict__ wgu,   // [E][2816][2048] fp32 codes
    const float* __restrict__ sgu,   // [E][22][16]
    const int* __restrict__ offs,
    const int* __restrict__ tok,
    float* __restrict__ h32) {
    int e = blockIdx.z;
    int mt = blockIdx.y;
    int jb = blockIdx.x;             // 0..21 (64-col pair tiles)
    int o0 = offs[e], o1 = offs[e + 1];
    int ne = o1 - o0;
    int m0 = mt * 64;
    if (m0 >= ne) return;

    __shared__ __align__(16) unsigned char Asm[64 * LDA];
    __shared__ __align__(16) unsigned char Bsm[128 * LDB];
    __shared__ float sxa[64 * 16];
    __shared__ int tokL[64];

    int tid = threadIdx.x;
    if (tid < 64) {
        int valid = tid < (ne - m0);
        tokL[tid] = valid ? tok[o0 + m0 + tid] : 0;
    }
    __syncthreads();
    {   // stage x scales for all 16 k-blocks
        int r = tid >> 2, q = tid & 3;
        *(float4*)(sxa + r * 16 + q * 4) =
            *(const float4*)(xs + tokL[r] * 16 + q * 4);
    }

    int wave = tid >> 6;
    int lane = tid & 63;
    int lr = lane & 15;
    int lq = lane >> 4;

    floatx4 facc[8], cacc[8];
    #pragma unroll
    for (int i = 0; i < 8; i++) facc[i] = fzero4();

    const int n0g = jb * 64;
    const int n0u = 1408 + jb * 64;
    const int sgi = (e * 22 + (jb >> 1)) * 16;
    const int sui = (e * 22 + 11 + (jb >> 1)) * 16;

    int ar = tid >> 2, aseg = tid & 3;       // A staging: row, 32B segment
    int br = tid >> 1, bhalf = tid & 1;      // B staging: row 0..127, 64-float half
    long bn = (br < 64) ? (long)(n0g + br) : (long)(n0u + (br - 64));
    const float* bptr = wgu + ((long)e * 2816 + bn) * 2048;
    const unsigned char* aptr = xq + (long)tokL[ar] * HD;

    for (int kb = 0; kb < 16; kb++) {
        {   // stage A codes (gathered rows)
            const uint4* src = (const uint4*)(aptr + kb * 128 + aseg * 32);
            uint4 d0 = src[0], d1 = src[1];
            *(uint4*)(&Asm[ar * LDA + aseg * 32]) = d0;
            *(uint4*)(&Asm[ar * LDA + aseg * 32 + 16]) = d1;
        }
        {   // stage B: 64 fp32 -> 64 fp8 codes
            const float4* src = (const float4*)(bptr + kb * 128 + bhalf * 64);
            #pragma unroll
            for (int g = 0; g < 4; g++) {
                unsigned int pk[4];
                #pragma unroll
                for (int u = 0; u < 4; u++) {
                    float4 f = src[g * 4 + u];
                    int p = __builtin_amdgcn_cvt_pk_fp8_f32(f.x, f.y, 0, false);
                    p = __builtin_amdgcn_cvt_pk_fp8_f32(f.z, f.w, p, true);
                    pk[u] = (unsigned int)p;
                }
                *(uint4*)(&Bsm[br * LDB + bhalf * 64 + g * 16]) =
                    make_uint4(pk[0], pk[1], pk[2], pk[3]);
            }
        }
        __syncthreads();
        #pragma unroll
        for (int i = 0; i < 8; i++) cacc[i] = fzero4();
        #pragma unroll
        for (int ks = 0; ks < 4; ks++) {
            long a = *(const long*)(&Asm[(wave * 16 + lr) * LDA + ks * 32 + lq * 8]);
            #pragma unroll
            for (int nt = 0; nt < 8; nt++) {
                int brow = (nt < 4) ? (nt * 16 + lr) : (64 + (nt - 4) * 16 + lr);
                long b = *(const long*)(&Bsm[brow * LDB + ks * 32 + lq * 8]);
                cacc[nt] = __builtin_amdgcn_mfma_f32_16x16x32_fp8_fp8(a, b, cacc[nt], 0, 0, 0);
            }
        }
        float sg = sgu[sgi + kb];
        float su = sgu[sui + kb];
        #pragma unroll
        for (int reg = 0; reg < 4; reg++) {
            float sx = sxa[(wave * 16 + lq * 4 + reg) * 16 + kb];
            #pragma unroll
            for (int nt = 0; nt < 8; nt++) {
                float sw = (nt < 4) ? sg : su;
                facc[nt][reg] += cacc[nt][reg] * (sw * sx);
            }
        }
        __syncthreads();
    }

    // epilogue: h = silu(gate) * up
    int colbase = jb * 64 + lr;
    #pragma unroll
    for (int nt = 0; nt < 4; nt++) {
        #pragma unroll
        for (int reg = 0; reg < 4; reg++) {
            int r = wave * 16 + lq * 4 + reg;
            if (r < ne - m0) {
                float g = facc[nt][reg];
                float u = facc[nt + 4][reg];
                float hval = (g / (1.0f + expf(-g))) * u;
                long j = o0 + m0 + r;
                h32[j * (long)ID + colbase + nt * 16] = hval;
            }
        }
    }
}

// ---------------- gemm2: routed h @ Wd^T, weighted atomic scatter ------------
__global__ __launch_bounds__(256) void gemm2_kernel(
    const unsigned char* __restrict__ hq,
    const float* __restrict__ hs,
    const float* __restrict__ wd,    // [E][2048][1408] fp32 codes
    const float* __restrict__ sd,    // [E][16][11]
    const int* __restrict__ offs,
    const int* __restrict__ tok,
    const float* __restrict__ wgt,
    float* __restrict__ out) {
    int e = blockIdx.z;
    int mt = blockIdx.y;
    int jb = blockIdx.x;             // 0..31 (64 H-cols each)
    int o0 = offs[e], o1 = offs[e + 1];
    int ne = o1 - o0;
    int m0 = mt * 64;
    if (m0 >= ne) return;

    __shared__ __align__(16) unsigned char Asm[64 * LDA];
    __shared__ __align__(16) unsigned char Bsm[64 * LDB];
    __shared__ float sha[64 * 12];
    __shared__ int tokL[64];
    __shared__ float wgtL[64];

    int tid = threadIdx.x;
    if (tid < 64) {
        int valid = tid < (ne - m0);
        int j = o0 + m0 + tid; if (j > 1023) j = 1023;
        tokL[tid] = valid ? tok[j] : 0;
        wgtL[tid] = valid ? wgt[j] : 0.0f;
    }
    for (int idx = tid; idx < 64 * 11; idx += 256) {
        int r = idx / 11, kb = idx - r * 11;
        int j = o0 + m0 + r; if (j > 1023) j = 1023;
        sha[r * 12 + kb] = hs[j * 11 + kb];
    }

    int wave = tid >> 6;
    int lane = tid & 63;
    int lr = lane & 15;
    int lq = lane >> 4;

    floatx4 facc[4], cacc[4];
    #pragma unroll
    for (int i = 0; i < 4; i++) facc[i] = fzero4();

    const int n0 = jb * 64;
    const int sdi = (e * 16 + (jb >> 1)) * 11;

    int ar = tid >> 2, aseg = tid & 3;
    long aj = o0 + m0 + ar; if (aj > 1023) aj = 1023;
    const unsigned char* aptr = hq + aj * ID;
    int br = tid >> 2, bq = tid & 3;         // B: 64 rows, 32-float quarters
    const float* bptr = wd + ((long)e * 2048 + n0 + br) * 1408;

    for (int kb = 0; kb < 11; kb++) {
        {
            const uint4* src = (const uint4*)(aptr + kb * 128 + aseg * 32);
            uint4 d0 = src[0], d1 = src[1];
            *(uint4*)(&Asm[ar * LDA + aseg * 32]) = d0;
            *(uint4*)(&Asm[ar * LDA + aseg * 32 + 16]) = d1;
        }
        {
            const float4* src = (const float4*)(bptr + kb * 128 + bq * 32);
            #pragma unroll
            for (int g = 0; g < 2; g++) {
                unsigned int pk[4];
                #pragma unroll
                for (int u = 0; u < 4; u++) {
                    float4 f = src[g * 4 + u];
                    int p = __builtin_amdgcn_cvt_pk_fp8_f32(f.x, f.y, 0, false);
                    p = __builtin_amdgcn_cvt_pk_fp8_f32(f.z, f.w, p, true);
                    pk[u] = (unsigned int)p;
                }
                *(uint4*)(&Bsm[br * LDB + bq * 32 + g * 16]) =
                    make_uint4(pk[0], pk[1], pk[2], pk[3]);
            }
        }
        __syncthreads();
        #pragma unroll
        for (int i = 0; i < 4; i++) cacc[i] = fzero4();
        #pragma unroll
        for (int ks = 0; ks < 4; ks++) {
            long a = *(const long*)(&Asm[(wave * 16 + lr) * LDA + ks * 32 + lq * 8]);
            #pragma unroll
            for (int nt = 0; nt < 4; nt++) {
                long b = *(const long*)(&Bsm[(nt * 16 + lr) * LDB + ks * 32 + lq * 8]);
                cacc[nt] = __builtin_amdgcn_mfma_f32_16x16x32_fp8_fp8(a, b, cacc[nt], 0, 0, 0);
            }
        }
        float sw = sd[sdi + kb];
        #pragma unroll
        for (int reg = 0; reg < 4; reg++) {
            float sh = sha[(wave * 16 + lq * 4 + reg) * 12 + kb];
            #pragma unroll
            for (int nt = 0; nt < 4; nt++) {
                facc[nt][reg] += cacc[nt][reg] * (sw * sh);
            }
        }
        __syncthreads();
    }

    #pragma unroll
    for (int nt = 0; nt < 4; nt++) {
        #pragma unroll
        for (int reg = 0; reg < 4; reg++) {
            int r = wave * 16 + lq * 4 + reg;
            if (r < ne - m0) {
                float v = facc[nt][reg] * wgtL[r];
                atomicAdd(out + (long)tokL[r] * HD + n0 + nt * 16 + lr, v);
            }
        }
    }
}

extern "C" void kernel_launch(void* const* d_in, const int* in_sizes, int n_in,
                              void* d_out, int out_size, void* d_ws, size_t ws_size,
                              hipStream_t stream) {
    (void)in_sizes; (void)n_in; (void)out_size; (void)ws_size;
    const float* x   = (const float*)d_in[0];
    const int*   tki = (const int*)d_in[1];
    const float* tkw = (const float*)d_in[2];
    const float* wgu = (const float*)d_in[3];
    const float* sgu = (const float*)d_in[4];
    const float* wd  = (const float*)d_in[5];
    const float* sd  = (const float*)d_in[6];
    float* out = (float*)d_out;
    char* ws = (char*)d_ws;

    int*   offs = (int*)(ws + OFF_OFFS);
    int*   tok  = (int*)(ws + OFF_TOK);
    float* wgt  = (float*)(ws + OFF_WGT);
    float* xs   = (float*)(ws + OFF_XS);
    unsigned char* xq = (unsigned char*)(ws + OFF_XQ);
    float* hs   = (float*)(ws + OFF_HS);
    unsigned char* hq = (unsigned char*)(ws + OFF_HQ);
    float* h32  = (float*)(ws + OFF_H32);

    hipMemsetAsync(d_out, 0, (size_t)NT * HD * sizeof(float), stream);
    route_kernel<<<1, 1024, 0, stream>>>(tki, tkw, offs, tok, wgt);
    quant_x_kernel<<<2048, 256, 0, stream>>>(x, xq, xs);
    gemm1_kernel<<<dim3(22, 16, NE), 256, 0, stream>>>(xq, xs, wgu, sgu, offs, tok, h32);
    quant_h_kernel<<<2816, 256, 0, stream>>>(h32, hq, hs);
    gemm2_kernel<<<dim3(32, 16, NE), 256, 0, stream>>>(hq, hs, wd, sd, offs, tok, wgt, out);
}

// Round 2
// 423.730 us; speedup vs baseline: 1.1732x; 1.1732x over previous
//
#include <hip/hip_runtime.h>
#include <math.h>

#define NE 8
#define HD 2048
#define ID 1408
#define NT 512
#define NENT 1024
#define FP8MAX 448.0f

typedef __attribute__((ext_vector_type(4))) float floatx4;

__device__ __forceinline__ floatx4 fzero4() {
    floatx4 z; z.x = 0.f; z.y = 0.f; z.z = 0.f; z.w = 0.f; return z;
}

// ---- ws layout (bytes), all 256-aligned (max ~9.6 MB, proven in round 0) ----
#define OFF_OFFS  0                         // int[16]
#define OFF_TOK   1024                      // int[1024]
#define OFF_WGT   8192                      // float[1024]
#define OFF_XS    16384                     // float[512*16]
#define OFF_XQ    65536                     // u8[512*2048]  (1 MiB)
#define OFF_HS    (2*1024*1024)             // float[1024*11]
#define OFF_HQ    (2*1024*1024 + 65536)     // u8[1024*1408]
#define OFF_H32   (4*1024*1024)             // float[1024*1408] (5.5 MiB)

#define LDA 136   // LDS row pitch for 128-byte fp8 rows (+8 pad: 2-way-free banks)

// ---------------- routing: build per-expert compact entry lists ----------------
__global__ void route_kernel(const int* __restrict__ tki,
                             const float* __restrict__ tkw,
                             int* __restrict__ offs,
                             int* __restrict__ tok,
                             float* __restrict__ wgt) {
    __shared__ int cnt[NE];
    __shared__ int cur[NE];
    __shared__ int base[NE + 1];
    int tid = threadIdx.x;               // 1024 threads, one per (token, slot)
    if (tid < NE) { cnt[tid] = 0; cur[tid] = 0; }
    __syncthreads();
    int e = tki[tid];
    atomicAdd(&cnt[e], 1);
    __syncthreads();
    if (tid == 0) {
        int s = 0;
        for (int i = 0; i < NE; i++) { base[i] = s; s += cnt[i]; }
        base[NE] = s;
    }
    __syncthreads();
    int pos = atomicAdd(&cur[e], 1);
    int j = base[e] + pos;
    tok[j] = tid >> 1;                   // token id
    wgt[j] = tkw[tid];
    if (tid <= NE) offs[tid] = base[tid];
}

// ---------------- activation quantization: wave per (token, 128-block) --------
__global__ void quant_x_kernel(const float* __restrict__ x,
                               unsigned char* __restrict__ xq,
                               float* __restrict__ xs) {
    int wid = (blockIdx.x * 256 + threadIdx.x) >> 6;   // 0..8191
    int lane = threadIdx.x & 63;
    int t = wid >> 4;
    int b = wid & 15;
    const float2 v = *(const float2*)(x + (long)t * HD + b * 128 + lane * 2);
    float am = fmaxf(fabsf(v.x), fabsf(v.y));
    #pragma unroll
    for (int m = 32; m; m >>= 1) am = fmaxf(am, __shfl_xor(am, m));
    float scale = fmaxf(am, 1e-12f) / FP8MAX;
    int p = __builtin_amdgcn_cvt_pk_fp8_f32(v.x / scale, v.y / scale, 0, false);
    *(unsigned short*)(xq + (long)t * HD + b * 128 + lane * 2) =
        (unsigned short)(p & 0xffff);
    if (lane == 0) xs[t * 16 + b] = scale;
}

// ---------------- h quantization: wave per (entry, 128-block of 11) ----------
__global__ void quant_h_kernel(const float* __restrict__ h32,
                               unsigned char* __restrict__ hq,
                               float* __restrict__ hs) {
    int wid = (blockIdx.x * 256 + threadIdx.x) >> 6;   // 0..11263
    int lane = threadIdx.x & 63;
    int j = wid / 11;
    int b = wid - j * 11;
    const float2 v = *(const float2*)(h32 + (long)j * ID + b * 128 + lane * 2);
    float am = fmaxf(fabsf(v.x), fabsf(v.y));
    #pragma unroll
    for (int m = 32; m; m >>= 1) am = fmaxf(am, __shfl_xor(am, m));
    float scale = fmaxf(am, 1e-12f) / FP8MAX;
    int p = __builtin_amdgcn_cvt_pk_fp8_f32(v.x / scale, v.y / scale, 0, false);
    *(unsigned short*)(hq + (long)j * ID + b * 128 + lane * 2) =
        (unsigned short)(p & 0xffff);
    if (lane == 0) hs[j * 11 + b] = scale;
}

// ---------------- gemm1: BM=256 entries x BN=32 gate/up col pairs ------------
// Each weight row is read from HBM exactly once in the typical (ne<=256) case.
__global__ __launch_bounds__(256) void gemm1_kernel(
    const unsigned char* __restrict__ xq,
    const float* __restrict__ xs,
    const float* __restrict__ wgu,   // [E][2816][2048] fp32 codes
    const float* __restrict__ sgu,   // [E][22][16]
    const int* __restrict__ offs,
    const int* __restrict__ tok,
    float* __restrict__ h32) {
    int e = blockIdx.z;
    int mt = blockIdx.y;
    int jb = blockIdx.x;             // 0..43 (32-col gate/up pair tiles)
    int o0 = offs[e], o1 = offs[e + 1];
    int ne = o1 - o0;
    int m0 = mt * 256;
    if (m0 >= ne) return;
    int rem = ne - m0;

    __shared__ __align__(16) unsigned char Asm[256 * LDA];  // 34816
    __shared__ __align__(16) unsigned char Bsm[64 * LDA];   // 8704
    __shared__ float sxa[256 * 16];                         // 16384
    __shared__ int tokL[256];

    int tid = threadIdx.x;
    {
        int j = o0 + m0 + tid;
        if (j >= o1) j = o0;           // pad rows: duplicate a valid entry
        tokL[tid] = tok[j];
    }
    __syncthreads();
    {   // stage per-row x scales for all 16 k-blocks
        const float4* s = (const float4*)(xs + tokL[tid] * 16);
        float4 a0 = s[0], a1 = s[1], a2 = s[2], a3 = s[3];
        float4* d = (float4*)(sxa + tid * 16);
        d[0] = a0; d[1] = a1; d[2] = a2; d[3] = a3;
    }

    int wave = tid >> 6;
    int lane = tid & 63;
    int lr = lane & 15;
    int lq = lane >> 4;

    const unsigned char* aptr = xq + (long)tokL[tid] * HD;
    int br = tid >> 2, bq = tid & 3;         // B: 64 rows, 32-float quarters
    long bn = (br < 32) ? (long)(jb * 32 + br)
                        : (long)(1408 + jb * 32 + (br - 32));
    const float* bptr = wgu + ((long)e * 2816 + bn) * 2048;
    const float* sgp = sgu + (e * 22 + (jb >> 2)) * 16;
    const float* sup = sgu + (e * 22 + 11 + (jb >> 2)) * 16;

    floatx4 facc[16];
    #pragma unroll
    for (int i = 0; i < 16; i++) facc[i] = fzero4();

    for (int kb = 0; kb < 16; kb++) {
        {   // stage A codes: each thread one gathered 128B row chunk
            const uint4* src = (const uint4*)(aptr + kb * 128);
            uint4 av[8];
            #pragma unroll
            for (int i = 0; i < 8; i++) av[i] = src[i];
            #pragma unroll
            for (int i = 0; i < 8; i++)
                *(uint4*)(&Asm[tid * LDA + i * 16]) = av[i];
        }
        {   // stage B: 32 fp32 -> 32 fp8 codes per thread
            const float4* src = (const float4*)(bptr + kb * 128 + bq * 32);
            unsigned int pk[8];
            #pragma unroll
            for (int g = 0; g < 8; g++) {
                float4 f = src[g];
                int p = __builtin_amdgcn_cvt_pk_fp8_f32(f.x, f.y, 0, false);
                p = __builtin_amdgcn_cvt_pk_fp8_f32(f.z, f.w, p, true);
                pk[g] = (unsigned int)p;
            }
            *(uint4*)(&Bsm[br * LDA + bq * 32]) =
                make_uint4(pk[0], pk[1], pk[2], pk[3]);
            *(uint4*)(&Bsm[br * LDA + bq * 32 + 16]) =
                make_uint4(pk[4], pk[5], pk[6], pk[7]);
        }
        __syncthreads();
        floatx4 cacc[16];
        #pragma unroll
        for (int i = 0; i < 16; i++) cacc[i] = fzero4();
        #pragma unroll
        for (int ks = 0; ks < 4; ks++) {
            long a[4], b[4];
            #pragma unroll
            for (int mi = 0; mi < 4; mi++)
                a[mi] = *(const long*)(&Asm[(wave * 64 + mi * 16 + lr) * LDA + ks * 32 + lq * 8]);
            #pragma unroll
            for (int ni = 0; ni < 4; ni++)
                b[ni] = *(const long*)(&Bsm[(ni * 16 + lr) * LDA + ks * 32 + lq * 8]);
            #pragma unroll
            for (int mi = 0; mi < 4; mi++)
                #pragma unroll
                for (int ni = 0; ni < 4; ni++)
                    cacc[mi * 4 + ni] = __builtin_amdgcn_mfma_f32_16x16x32_fp8_fp8(
                        a[mi], b[ni], cacc[mi * 4 + ni], 0, 0, 0);
        }
        float sg = sgp[kb];
        float su = sup[kb];
        #pragma unroll
        for (int mi = 0; mi < 4; mi++) {
            #pragma unroll
            for (int reg = 0; reg < 4; reg++) {
                float sx = sxa[(wave * 64 + mi * 16 + lq * 4 + reg) * 16 + kb];
                #pragma unroll
                for (int ni = 0; ni < 4; ni++) {
                    float sw = (ni < 2) ? sg : su;
                    facc[mi * 4 + ni][reg] += cacc[mi * 4 + ni][reg] * (sw * sx);
                }
            }
        }
        __syncthreads();
    }

    // epilogue: h = silu(gate) * up   (ni 0,1 = gate; ni 2,3 = matching up)
    #pragma unroll
    for (int mi = 0; mi < 4; mi++) {
        #pragma unroll
        for (int ni = 0; ni < 2; ni++) {
            #pragma unroll
            for (int reg = 0; reg < 4; reg++) {
                int r = wave * 64 + mi * 16 + lq * 4 + reg;
                if (r < rem) {
                    float g = facc[mi * 4 + ni][reg];
                    float u = facc[mi * 4 + ni + 2][reg];
                    float hval = (g / (1.0f + expf(-g))) * u;
                    h32[(long)(o0 + m0 + r) * ID + jb * 32 + ni * 16 + lr] = hval;
                }
            }
        }
    }
}

// ---------------- gemm2: BM=256 entries x BN=64 H-cols, weighted scatter -----
__global__ __launch_bounds__(256) void gemm2_kernel(
    const unsigned char* __restrict__ hq,
    const float* __restrict__ hs,
    const float* __restrict__ wd,    // [E][2048][1408] fp32 codes
    const float* __restrict__ sd,    // [E][16][11]
    const int* __restrict__ offs,
    const int* __restrict__ tok,
    const float* __restrict__ wgt,
    float* __restrict__ out) {
    int e = blockIdx.z;
    int mt = blockIdx.y;
    int jb = blockIdx.x;             // 0..31 (64 H-cols each)
    int o0 = offs[e], o1 = offs[e + 1];
    int ne = o1 - o0;
    int m0 = mt * 256;
    if (m0 >= ne) return;
    int rem = ne - m0;

    __shared__ __align__(16) unsigned char Asm[256 * LDA];  // 34816
    __shared__ __align__(16) unsigned char Bsm[64 * LDA];   // 8704
    __shared__ float sha[256 * 12];                         // 12288
    __shared__ int tokL[256];
    __shared__ float wgtL[256];

    int tid = threadIdx.x;
    int jent;
    {
        int j = o0 + m0 + tid;
        int valid = j < o1;
        if (!valid) j = o0;
        jent = j;
        tokL[tid] = tok[j];
        wgtL[tid] = valid ? wgt[j] : 0.0f;
    }
    {   // per-row h scales (11 k-blocks)
        const float* s = hs + jent * 11;
        #pragma unroll
        for (int k = 0; k < 11; k++) sha[tid * 12 + k] = s[k];
    }

    int wave = tid >> 6;
    int lane = tid & 63;
    int lr = lane & 15;
    int lq = lane >> 4;

    const unsigned char* aptr = hq + (long)jent * ID;
    int br = tid >> 2, bq = tid & 3;
    const float* bptr = wd + ((long)e * 2048 + jb * 64 + br) * 1408;
    const float* sdp = sd + (e * 16 + (jb >> 1)) * 11;

    floatx4 facc[16];
    #pragma unroll
    for (int i = 0; i < 16; i++) facc[i] = fzero4();

    for (int kb = 0; kb < 11; kb++) {
        {
            const uint4* src = (const uint4*)(aptr + kb * 128);
            uint4 av[8];
            #pragma unroll
            for (int i = 0; i < 8; i++) av[i] = src[i];
            #pragma unroll
            for (int i = 0; i < 8; i++)
                *(uint4*)(&Asm[tid * LDA + i * 16]) = av[i];
        }
        {
            const float4* src = (const float4*)(bptr + kb * 128 + bq * 32);
            unsigned int pk[8];
            #pragma unroll
            for (int g = 0; g < 8; g++) {
                float4 f = src[g];
                int p = __builtin_amdgcn_cvt_pk_fp8_f32(f.x, f.y, 0, false);
                p = __builtin_amdgcn_cvt_pk_fp8_f32(f.z, f.w, p, true);
                pk[g] = (unsigned int)p;
            }
            *(uint4*)(&Bsm[br * LDA + bq * 32]) =
                make_uint4(pk[0], pk[1], pk[2], pk[3]);
            *(uint4*)(&Bsm[br * LDA + bq * 32 + 16]) =
                make_uint4(pk[4], pk[5], pk[6], pk[7]);
        }
        __syncthreads();
        floatx4 cacc[16];
        #pragma unroll
        for (int i = 0; i < 16; i++) cacc[i] = fzero4();
        #pragma unroll
        for (int ks = 0; ks < 4; ks++) {
            long a[4], b[4];
            #pragma unroll
            for (int mi = 0; mi < 4; mi++)
                a[mi] = *(const long*)(&Asm[(wave * 64 + mi * 16 + lr) * LDA + ks * 32 + lq * 8]);
            #pragma unroll
            for (int ni = 0; ni < 4; ni++)
                b[ni] = *(const long*)(&Bsm[(ni * 16 + lr) * LDA + ks * 32 + lq * 8]);
            #pragma unroll
            for (int mi = 0; mi < 4; mi++)
                #pragma unroll
                for (int ni = 0; ni < 4; ni++)
                    cacc[mi * 4 + ni] = __builtin_amdgcn_mfma_f32_16x16x32_fp8_fp8(
                        a[mi], b[ni], cacc[mi * 4 + ni], 0, 0, 0);
        }
        float sw = sdp[kb];
        #pragma unroll
        for (int mi = 0; mi < 4; mi++) {
            #pragma unroll
            for (int reg = 0; reg < 4; reg++) {
                float sh = sha[(wave * 64 + mi * 16 + lq * 4 + reg) * 12 + kb];
                #pragma unroll
                for (int ni = 0; ni < 4; ni++)
                    facc[mi * 4 + ni][reg] += cacc[mi * 4 + ni][reg] * (sw * sh);
            }
        }
        __syncthreads();
    }

    #pragma unroll
    for (int mi = 0; mi < 4; mi++) {
        #pragma unroll
        for (int ni = 0; ni < 4; ni++) {
            #pragma unroll
            for (int reg = 0; reg < 4; reg++) {
                int r = wave * 64 + mi * 16 + lq * 4 + reg;
                if (r < rem) {
                    float v = facc[mi * 4 + ni][reg] * wgtL[r];
                    atomicAdd(out + (long)tokL[r] * HD + jb * 64 + ni * 16 + lr, v);
                }
            }
        }
    }
}

extern "C" void kernel_launch(void* const* d_in, const int* in_sizes, int n_in,
                              void* d_out, int out_size, void* d_ws, size_t ws_size,
                              hipStream_t stream) {
    (void)in_sizes; (void)n_in; (void)out_size; (void)ws_size;
    const float* x   = (const float*)d_in[0];
    const int*   tki = (const int*)d_in[1];
    const float* tkw = (const float*)d_in[2];
    const float* wgu = (const float*)d_in[3];
    const float* sgu = (const float*)d_in[4];
    const float* wd  = (const float*)d_in[5];
    const float* sd  = (const float*)d_in[6];
    float* out = (float*)d_out;
    char* ws = (char*)d_ws;

    int*   offs = (int*)(ws + OFF_OFFS);
    int*   tok  = (int*)(ws + OFF_TOK);
    float* wgt  = (float*)(ws + OFF_WGT);
    float* xs   = (float*)(ws + OFF_XS);
    unsigned char* xq = (unsigned char*)(ws + OFF_XQ);
    float* hs   = (float*)(ws + OFF_HS);
    unsigned char* hq = (unsigned char*)(ws + OFF_HQ);
    float* h32  = (float*)(ws + OFF_H32);

    hipMemsetAsync(d_out, 0, (size_t)NT * HD * sizeof(float), stream);
    route_kernel<<<1, 1024, 0, stream>>>(tki, tkw, offs, tok, wgt);
    quant_x_kernel<<<2048, 256, 0, stream>>>(x, xq, xs);
    gemm1_kernel<<<dim3(44, 4, NE), 256, 0, stream>>>(xq, xs, wgu, sgu, offs, tok, h32);
    quant_h_kernel<<<2816, 256, 0, stream>>>(h32, hq, hs);
    gemm2_kernel<<<dim3(32, 4, NE), 256, 0, stream>>>(hq, hs, wd, sd, offs, tok, wgt, out);
}